// Round 15
// baseline (951.834 us; speedup 1.0000x reference)
//
#include <hip/hip_runtime.h>

typedef __attribute__((ext_vector_type(8))) short s8v;
typedef __attribute__((ext_vector_type(4))) float f32x4;

#define MFMA16(A,B,C) __builtin_amdgcn_mfma_f32_16x16x32_bf16((A),(B),(C),0,0,0)

__device__ __forceinline__ float b2f(unsigned short s){
  union { unsigned u; float f; } v; v.u = ((unsigned)s) << 16; return v.f;
}
// 2-op bf16 convert (round-half-up)
__device__ __forceinline__ unsigned short f2b(float f){
  union { float f; unsigned u; } v; v.f = f;
  return (unsigned short)((v.u + 0x8000u) >> 16);
}
// silu via v_rcp_f32 (1 ulp) instead of IEEE division sequence
__device__ __forceinline__ float siluf(float x){
  return x * __builtin_amdgcn_rcpf(1.f + __expf(-x));
}

// ---------- CSR build (edge list identical every call) ----------

__global__ void hist_kernel(const int* __restrict__ dst, int* __restrict__ deg, int E){
  int i = blockIdx.x*256 + threadIdx.x;
  if (i < E) atomicAdd(&deg[dst[i]], 1);
}

__global__ void scan1_kernel(const int* __restrict__ deg, int* __restrict__ rp,
                             int* __restrict__ bsum, int N){
  __shared__ int s[256];
  const int base = blockIdx.x*1024;
  const int t = threadIdx.x;
  int v[4];
  #pragma unroll
  for (int j = 0; j < 4; ++j){
    int idx = base + t*4 + j;
    v[j] = (idx < N) ? deg[idx] : 0;
  }
  const int tsum = v[0]+v[1]+v[2]+v[3];
  s[t] = tsum;
  __syncthreads();
  for (int off = 1; off < 256; off <<= 1){
    int x = (t >= off) ? s[t-off] : 0;
    __syncthreads();
    s[t] += x;
    __syncthreads();
  }
  const int incl = s[t];
  if (t == 255) bsum[blockIdx.x] = incl;
  int run = incl - tsum;
  #pragma unroll
  for (int j = 0; j < 4; ++j){
    int idx = base + t*4 + j;
    if (idx < N) rp[idx] = run;
    run += v[j];
  }
}

__global__ void scan2_kernel(int* __restrict__ bsum, int nb){
  __shared__ int s[256];
  const int t = threadIdx.x;
  const int v = (t < nb) ? bsum[t] : 0;
  s[t] = v;
  __syncthreads();
  for (int off = 1; off < 256; off <<= 1){
    int x = (t >= off) ? s[t-off] : 0;
    __syncthreads();
    s[t] += x;
    __syncthreads();
  }
  if (t < nb) bsum[t] = s[t] - v;
}

__global__ void scan3_kernel(int* __restrict__ rp, const int* __restrict__ bsum,
                             int N, int E){
  int i = blockIdx.x*256 + threadIdx.x;
  if (i < N) rp[i] += bsum[i >> 10];
  if (i == 0) rp[N] = E;
}

__global__ void scatter_kernel(const int* __restrict__ src, const int* __restrict__ dst,
                               const int* __restrict__ rp, int* __restrict__ cursor,
                               int* __restrict__ csr_src, int E){
  int i = blockIdx.x*256 + threadIdx.x;
  if (i < E){
    const int d = dst[i];
    const int pos = rp[d] + atomicAdd(&cursor[d], 1);
    csr_src[pos] = src[i];
  }
}

// ---------- small prologue kernels (inputs are fp32 — R4..R13 evidence) ----------

__global__ void tmean_kernel(const float* __restrict__ t,
                             const float* __restrict__ tw1,
                             const float* __restrict__ tb1,
                             const float* __restrict__ tw2,
                             const float* __restrict__ tb2,
                             float* __restrict__ tmean){
  __shared__ __align__(16) float s1[16*64];
  int j = threadIdx.x;
  float w1 = tw1[j], bb1 = tb1[j];
  for (int b = 0; b < 16; ++b)
    s1[b*64 + j] = siluf(t[b] * w1 + bb1);
  __syncthreads();
  float acc = 0.f;
  for (int b = 0; b < 16; ++b)
    for (int k = 0; k < 64; ++k)
      acc += s1[b*64 + k] * tw2[k*64 + j];
  tmean[j] = tb2[j] + acc * (1.f/16.f);
}

// h kept in bf16 only (residual rounding ~1e-3/layer; headroom 4.5x)
__global__ void init_h_kernel(const int* __restrict__ z,
                              const float* __restrict__ emb,
                              const float* __restrict__ tmean,
                              unsigned short* __restrict__ hb, int N){
  int i = blockIdx.x*256 + threadIdx.x;
  if (i >= N*64) return;
  int j = i & 63;
  int n = i >> 6;
  hb[i] = f2b(emb[z[n]*64 + j] + tmean[j]);
}

// ---------- p12: per-node MLP1 partials (layer 0 only; 1,2 fused into node) ----

__global__ __launch_bounds__(512) void p12_kernel(
    const unsigned short* __restrict__ hb,
    const float* __restrict__ ew1, const float* __restrict__ eb1,
    unsigned short* __restrict__ P1, unsigned short* __restrict__ P2,
    int layer, int N)
{
  __shared__ __align__(16) short w1a[64*72];
  __shared__ __align__(16) short w1b[64*72];
  __shared__ __align__(16) float b1s[64];

  const int tid = threadIdx.x;
  const float* w1g = ew1 + layer*129*64;
  for (int idx = tid; idx < 64*64; idx += 512){
    int k = idx >> 6, n = idx & 63;
    w1a[n*72 + k] = (short)f2b(w1g[k*64 + n]);
    w1b[n*72 + k] = (short)f2b(w1g[(64 + k)*64 + n]);
  }
  if (tid < 64) b1s[tid] = eb1[layer*64 + tid];
  __syncthreads();

  const int lane = tid & 63;
  const int wv = tid >> 6;
  const int q = lane >> 4;
  const int n16 = lane & 15;

  const int ntile = N >> 4;
  const int step = gridDim.x * 8;
  for (int t = blockIdx.x*8 + wv; t < ntile; t += step){
    const int row = t*16 + n16;
    const s8v* ph = (const s8v*)(hb + row*64);
    const s8v a0 = ph[q];
    const s8v a1 = ph[4+q];
    #pragma unroll
    for (int nt = 0; nt < 4; ++nt){
      const s8v* wa = (const s8v*)&w1a[(nt*16 + n16)*72];
      const s8v* wb = (const s8v*)&w1b[(nt*16 + n16)*72];
      f32x4 aA = {0.f,0.f,0.f,0.f};
      aA = MFMA16(a0, wa[q],   aA);
      aA = MFMA16(a1, wa[4+q], aA);
      f32x4 aB = {0.f,0.f,0.f,0.f};
      aB = MFMA16(a0, wb[q],   aB);
      aB = MFMA16(a1, wb[4+q], aB);
      const float bb = b1s[nt*16 + n16];
      #pragma unroll
      for (int r = 0; r < 4; ++r){
        const int o = (t*16 + q*4 + r)*64 + nt*16 + n16;
        P1[o] = f2b(aA[r] + bb);
        P2[o] = f2b(aB[r]);
      }
    }
  }
}

// ---------- edge kernel (CSR): one wave per dst node, NO atomics ----------
// (identical to the proven 231 µs / VGPR 64 version, plus uniform do_agg guard)

__global__ __launch_bounds__(512) void edge_csr_kernel(
    const int* __restrict__ rp, const int* __restrict__ csr_src,
    const float* __restrict__ x_in, float* __restrict__ x_out,
    const unsigned short* __restrict__ P1, const unsigned short* __restrict__ P2,
    unsigned short* __restrict__ aggb,
    const float* __restrict__ ew1,
    const float* __restrict__ ew2, const float* __restrict__ eb2,
    const float* __restrict__ cw1, const float* __restrict__ cb1,
    const float* __restrict__ cw2, const float* __restrict__ cb2,
    int layer, int do_agg, int N)
{
  __shared__ __align__(16) short wT2[64*72];    // e_w2^T [n][k]
  __shared__ __align__(16) short wc1T[64*72];   // c_w1^T
  __shared__ __align__(16) short sc[8][16*72];  // per-wave C->A transpose scratch
  __shared__ __align__(16) float sdiff[8][48];

  const int tid = threadIdx.x;
  const float* w2g = ew2 + layer*64*64;
  const float* c1g = cw1 + layer*64*64;
  for (int idx = tid; idx < 64*64; idx += 512){
    int k = idx >> 6, n = idx & 63;
    wT2[n*72 + k]  = (short)f2b(w2g[k*64 + n]);
    wc1T[n*72 + k] = (short)f2b(c1g[k*64 + n]);
  }

  const int lane = tid & 63;
  const int wv = tid >> 6;       // 0..7
  const int q = lane >> 4;       // quad 0..3
  const int n16 = lane & 15;
  short* mysc = sc[wv];
  float* mydiff = sdiff[wv];

  // per-lane loop-invariant constants in registers
  const float* wlg = ew1 + layer*129*64 + 128*64;
  float wl_lo[8], wl_hi[8];
  #pragma unroll
  for (int j = 0; j < 8; ++j){
    wl_lo[j] = wlg[q*8 + j];
    wl_hi[j] = wlg[32 + q*8 + j];
  }
  float be2r[4], bc1r[4], cw2r[4];
  #pragma unroll
  for (int nt = 0; nt < 4; ++nt){
    be2r[nt] = eb2[layer*64 + nt*16 + n16];
    bc1r[nt] = cb1[layer*64 + nt*16 + n16];
    cw2r[nt] = cw2[layer*64 + nt*16 + n16];
  }
  const float cb2s = cb2[layer];
  __syncthreads();

  const int nwave = gridDim.x * 8;
  for (int n = blockIdx.x*8 + wv; n < N; n += nwave){
    const int start = rp[n];
    const int deg = rp[n+1] - start;

    const s8v* pd = (const s8v*)(P1 + (size_t)n*64);
    const s8v lo1 = pd[q];
    const s8v hi1 = pd[4+q];
    const float xd0 = x_in[n*3+0];
    const float xd1 = x_in[n*3+1];
    const float xd2 = x_in[n*3+2];

    float colsum[4] = {0.f,0.f,0.f,0.f};
    float xacc0 = 0.f, xacc1 = 0.f, xacc2 = 0.f;

    const int nch = (deg + 15) >> 4;
    for (int c = 0; c < nch; ++c){
      const int row = c*16 + n16;
      const int si = (row < deg) ? csr_src[start + row] : n;  // pad: self -> diff=0
      const float xs0 = x_in[si*3+0];
      const float xs1 = x_in[si*3+1];
      const float xs2 = x_in[si*3+2];
      const float dx = xd0 - xs0;
      const float dy = xd1 - xs1;
      const float dz = xd2 - xs2;
      const float d2 = dx*dx + dy*dy + dz*dz;
      if (q == 0){ mydiff[n16*3+0]=dx; mydiff[n16*3+1]=dy; mydiff[n16*3+2]=dz; }

      const s8v* ps = (const s8v*)(P2 + (size_t)si*64);
      const s8v lo2 = ps[q];
      const s8v hi2 = ps[4+q];

      // MLP1 combine in registers (A-layout)
      s8v alo, ahi;
      #pragma unroll
      for (int j = 0; j < 8; ++j){
        const float v0 = b2f((unsigned short)lo1[j]) + b2f((unsigned short)lo2[j]) + d2*wl_lo[j];
        alo[j] = (short)f2b(siluf(v0));
        const float v1 = b2f((unsigned short)hi1[j]) + b2f((unsigned short)hi2[j]) + d2*wl_hi[j];
        ahi[j] = (short)f2b(siluf(v1));
      }

      // MLP2: (16x64)@(64x64)
      f32x4 acc2[4];
      #pragma unroll
      for (int nt = 0; nt < 4; ++nt){
        const s8v* wb = (const s8v*)&wT2[(nt*16 + n16)*72];
        f32x4 a = {0.f,0.f,0.f,0.f};
        a = MFMA16(alo, wb[q],   a);
        a = MFMA16(ahi, wb[4+q], a);
        acc2[nt] = a;
      }
      const int rowbase = c*16 + q*4;
      #pragma unroll
      for (int nt = 0; nt < 4; ++nt){
        const float bb = be2r[nt];
        #pragma unroll
        for (int r = 0; r < 4; ++r){
          const float mv = siluf(acc2[nt][r] + bb);
          mysc[(q*4 + r)*72 + nt*16 + n16] = (short)f2b(mv);
          if (do_agg) colsum[nt] += (rowbase + r < deg) ? mv : 0.f;
        }
      }
      __builtin_amdgcn_wave_barrier();
      const s8v* srd = (const s8v*)&mysc[n16*72];
      const s8v m0 = srd[q];
      const s8v m1 = srd[4+q];
      __builtin_amdgcn_wave_barrier();

      // coord MLP: silu(m@c_w1+b) @ c_w2 + b
      float pr[4] = {0.f,0.f,0.f,0.f};
      #pragma unroll
      for (int nt = 0; nt < 4; ++nt){
        const s8v* wb = (const s8v*)&wc1T[(nt*16 + n16)*72];
        f32x4 a = {0.f,0.f,0.f,0.f};
        a = MFMA16(m0, wb[q],   a);
        a = MFMA16(m1, wb[4+q], a);
        const float bc = bc1r[nt];
        const float wc2 = cw2r[nt];
        #pragma unroll
        for (int r = 0; r < 4; ++r) pr[r] += siluf(a[r] + bc) * wc2;
      }
      #pragma unroll
      for (int off = 1; off < 16; off <<= 1){
        #pragma unroll
        for (int r = 0; r < 4; ++r) pr[r] += __shfl_xor(pr[r], off, 64);
      }
      #pragma unroll
      for (int r = 0; r < 4; ++r){
        const float cwv = pr[r] + cb2s;
        xacc0 += mydiff[(q*4 + r)*3 + 0] * cwv;
        xacc1 += mydiff[(q*4 + r)*3 + 1] * cwv;
        xacc2 += mydiff[(q*4 + r)*3 + 2] * cwv;
      }
    }

    if (do_agg){
      #pragma unroll
      for (int nt = 0; nt < 4; ++nt){
        colsum[nt] += __shfl_xor(colsum[nt], 16, 64);
        colsum[nt] += __shfl_xor(colsum[nt], 32, 64);
      }
    }
    xacc0 += __shfl_xor(xacc0, 16, 64); xacc0 += __shfl_xor(xacc0, 32, 64);
    xacc1 += __shfl_xor(xacc1, 16, 64); xacc1 += __shfl_xor(xacc1, 32, 64);
    xacc2 += __shfl_xor(xacc2, 16, 64); xacc2 += __shfl_xor(xacc2, 32, 64);

    if (do_agg && q == 0){
      #pragma unroll
      for (int nt = 0; nt < 4; ++nt)
        aggb[(size_t)n*64 + nt*16 + n16] = f2b(colsum[nt]);
    }
    if (lane == 0){
      x_out[n*3+0] = xd0 + xacc0;
      x_out[n*3+1] = xd1 + xacc1;
      x_out[n*3+2] = xd2 + xacc2;
    }
  }
}

// ---------- fused node + p12(next layer), bf16-only h ----------

__global__ __launch_bounds__(512) void node_p12_kernel(
    unsigned short* __restrict__ hb,
    const unsigned short* __restrict__ aggb,
    const float* __restrict__ nw1, const float* __restrict__ nb1,
    const float* __restrict__ nw2, const float* __restrict__ nb2,
    const float* __restrict__ ew1, const float* __restrict__ eb1,
    unsigned short* __restrict__ P1, unsigned short* __restrict__ P2,
    int layer, int N)   // node layer = layer; p12 weights = layer+1
{
  __shared__ __align__(16) short wT1[64*136];
  __shared__ __align__(16) short wT2[64*72];
  __shared__ __align__(16) short w1a[64*72];
  __shared__ __align__(16) short w1b[64*72];
  __shared__ __align__(16) short sc[8][16*72];
  __shared__ __align__(16) float b1s[64];
  __shared__ __align__(16) float b2s[64];
  __shared__ __align__(16) float eb1s[64];

  const int tid = threadIdx.x;
  const float* w1g = nw1 + layer*128*64;
  const float* w2g = nw2 + layer*64*64;
  const float* e1g = ew1 + (layer+1)*129*64;
  for (int idx = tid; idx < 64*128; idx += 512){
    int k = idx >> 6, n = idx & 63;
    wT1[n*136 + k] = (short)f2b(w1g[k*64 + n]);
  }
  for (int idx = tid; idx < 64*64; idx += 512){
    int k = idx >> 6, n = idx & 63;
    wT2[n*72 + k] = (short)f2b(w2g[k*64 + n]);
    w1a[n*72 + k] = (short)f2b(e1g[k*64 + n]);
    w1b[n*72 + k] = (short)f2b(e1g[(64 + k)*64 + n]);
  }
  if (tid < 64){
    b1s[tid]  = nb1[layer*64 + tid];
    b2s[tid]  = nb2[layer*64 + tid];
    eb1s[tid] = eb1[(layer+1)*64 + tid];
  }
  __syncthreads();

  const int lane = tid & 63;
  const int wv = tid >> 6;
  const int q = lane >> 4;
  const int n16 = lane & 15;
  short* mysc = sc[wv];

  const int ntile = N >> 4;
  const int step = gridDim.x * 8;
  for (int t = blockIdx.x*8 + wv; t < ntile; t += step){
    const int row = t*16 + n16;
    const s8v* ph = (const s8v*)(hb + row*64);
    const s8v a0 = ph[q];
    const s8v a1 = ph[4+q];
    const s8v* pa = (const s8v*)(aggb + (size_t)row*64);
    const s8v a2 = pa[q];
    const s8v a3 = pa[4+q];

    // phase 1: g = silu([h|agg] @ n_w1 + b1) -> LDS (C->A transpose)
    #pragma unroll
    for (int nt = 0; nt < 4; ++nt){
      const s8v* wb = (const s8v*)&wT1[(nt*16 + n16)*136];
      f32x4 a = {0.f,0.f,0.f,0.f};
      a = MFMA16(a0, wb[q],    a);
      a = MFMA16(a1, wb[4+q],  a);
      a = MFMA16(a2, wb[8+q],  a);
      a = MFMA16(a3, wb[12+q], a);
      const float bb = b1s[nt*16 + n16];
      #pragma unroll
      for (int r = 0; r < 4; ++r)
        mysc[(q*4 + r)*72 + nt*16 + n16] = (short)f2b(siluf(a[r] + bb));
    }
    __builtin_amdgcn_wave_barrier();
    const s8v* srd = (const s8v*)&mysc[n16*72];
    const s8v g0 = srd[q];
    const s8v g1 = srd[4+q];
    __builtin_amdgcn_wave_barrier();

    // phase 2: h' = h + g @ n_w2 + b2 (residual read from bf16 hb, C-layout)
    #pragma unroll
    for (int nt = 0; nt < 4; ++nt){
      const s8v* wb = (const s8v*)&wT2[(nt*16 + n16)*72];
      f32x4 a = {0.f,0.f,0.f,0.f};
      a = MFMA16(g0, wb[q],   a);
      a = MFMA16(g1, wb[4+q], a);
      const float bb = b2s[nt*16 + n16];
      #pragma unroll
      for (int r = 0; r < 4; ++r){
        const int idx = (t*16 + q*4 + r)*64 + nt*16 + n16;
        const float hv = b2f(hb[idx]) + a[r] + bb;
        const unsigned short hvb = f2b(hv);
        hb[idx] = hvb;
        mysc[(q*4 + r)*72 + nt*16 + n16] = (short)hvb;
      }
    }
    __builtin_amdgcn_wave_barrier();
    const s8v h0 = srd[q];
    const s8v h1 = srd[4+q];
    __builtin_amdgcn_wave_barrier();

    // phase 3: P1/P2 for layer+1 from h' (A-layout)
    #pragma unroll
    for (int nt = 0; nt < 4; ++nt){
      const s8v* wa = (const s8v*)&w1a[(nt*16 + n16)*72];
      const s8v* wb = (const s8v*)&w1b[(nt*16 + n16)*72];
      f32x4 aA = {0.f,0.f,0.f,0.f};
      aA = MFMA16(h0, wa[q],   aA);
      aA = MFMA16(h1, wa[4+q], aA);
      f32x4 aB = {0.f,0.f,0.f,0.f};
      aB = MFMA16(h0, wb[q],   aB);
      aB = MFMA16(h1, wb[4+q], aB);
      const float bb = eb1s[nt*16 + n16];
      #pragma unroll
      for (int r = 0; r < 4; ++r){
        const int o = (t*16 + q*4 + r)*64 + nt*16 + n16;
        P1[o] = f2b(aA[r] + bb);
        P2[o] = f2b(aB[r]);
      }
    }
  }
}

// ---------- launch ----------

extern "C" void kernel_launch(void* const* d_in, const int* in_sizes, int n_in,
                              void* d_out, int out_size, void* d_ws, size_t ws_size,
                              hipStream_t stream)
{
  // Inputs are fp32 (established R4..R13). Read d_in directly.
  const float* x0   = (const float*)d_in[0];
  const int*   z    = (const int*)d_in[1];
  const float* tc   = (const float*)d_in[2];
  const int*   ei   = (const int*)d_in[3];
  const float* embc = (const float*)d_in[4];
  const float* tw1c = (const float*)d_in[5];
  const float* tb1c = (const float*)d_in[6];
  const float* tw2c = (const float*)d_in[7];
  const float* tb2c = (const float*)d_in[8];
  const float* ew1c = (const float*)d_in[9];
  const float* eb1c = (const float*)d_in[10];
  const float* ew2c = (const float*)d_in[11];
  const float* eb2c = (const float*)d_in[12];
  const float* cw1c = (const float*)d_in[13];
  const float* cb1c = (const float*)d_in[14];
  const float* cw2c = (const float*)d_in[15];
  const float* cb2c = (const float*)d_in[16];
  const float* nw1c = (const float*)d_in[17];
  const float* nb1c = (const float*)d_in[18];
  const float* nw2c = (const float*)d_in[19];
  const float* nb2c = (const float*)d_in[20];

  const int N = in_sizes[1];
  const int E = in_sizes[3] / 2;
  const int* srcp = ei;
  const int* dstp = ei + E;

  char* p = (char*)d_ws;
  auto alloc = [&](size_t bytes) -> void* {
    void* r = (void*)p; p += (bytes + 255) & ~(size_t)255; return r;
  };
  unsigned short* hbuf = (unsigned short*)alloc((size_t)N*64*2);
  unsigned short* aggb = (unsigned short*)alloc((size_t)N*64*2);
  unsigned short* P1   = (unsigned short*)alloc((size_t)N*64*2);
  unsigned short* P2   = (unsigned short*)alloc((size_t)N*64*2);
  float* xa            = (float*)alloc((size_t)N*3*4);
  float* xb            = (float*)alloc((size_t)N*3*4);
  float* tmean         = (float*)alloc(64*4);
  int*   degcur        = (int*)alloc((size_t)2*N*4);   // deg | cursor (one memset)
  int*   deg           = degcur;
  int*   cursor        = degcur + N;
  int*   rowp          = (int*)alloc((size_t)(N+1)*4);
  int*   bsum          = (int*)alloc(256*4);
  int*   csr_src       = (int*)alloc((size_t)E*4);

  tmean_kernel<<<1, 64, 0, stream>>>(tc, tw1c, tb1c, tw2c, tb2c, tmean);
  init_h_kernel<<<(N*64 + 255)/256, 256, 0, stream>>>(z, embc, tmean, hbuf, N);

  // ---- CSR build (once; edges fixed across layers) ----
  (void)hipMemsetAsync(degcur, 0, (size_t)2*N*4, stream);
  hist_kernel<<<(E + 255)/256, 256, 0, stream>>>(dstp, deg, E);
  const int nb = (N + 1023)/1024;
  scan1_kernel<<<nb, 256, 0, stream>>>(deg, rowp, bsum, N);
  scan2_kernel<<<1, 256, 0, stream>>>(bsum, nb);
  scan3_kernel<<<(N + 255)/256, 256, 0, stream>>>(rowp, bsum, N, E);
  scatter_kernel<<<(E + 255)/256, 256, 0, stream>>>(srcp, dstp, rowp, cursor, csr_src, E);

  // layer-0 partials standalone; layers 1,2 fused into node_p12
  p12_kernel<<<512, 512, 0, stream>>>(hbuf, ew1c, eb1c, P1, P2, 0, N);

  const float* xc = x0;
  float* xnexts[3] = {xa, xb, (float*)d_out};
  for (int l = 0; l < 3; ++l){
    float* xout = xnexts[l];
    edge_csr_kernel<<<1024, 512, 0, stream>>>(rowp, csr_src, xc, xout, P1, P2, aggb,
        ew1c, ew2c, eb2c, cw1c, cb1c, cw2c, cb2c, l, (l < 2) ? 1 : 0, N);
    if (l < 2)
      node_p12_kernel<<<512, 512, 0, stream>>>(hbuf, aggb,
          nw1c, nb1c, nw2c, nb2c, ew1c, eb1c, P1, P2, l, N);
    xc = xout;
  }
}